// Round 7
// baseline (37.123 us; speedup 1.0000x reference)
//
#include <hip/hip_runtime.h>
#include <math.h>

#define NB 768
#define ND 128
#define NC 12            // NB / 64 lane-chunks (mining layout)
#define APB 3            // anchors per block -> grid = 256 = one block per CU
#define TL_MARGIN 1.0f
#define TL_EPS 1e-12f

// ws layout (bytes):
//   ET @ 0x00000 : 128*768 f32 = 384 KB   (ET[k][j] = E[j][k])
//   sq @ 0x60000 : 768 f32                (sq[j] = ||E[j]||^2)
//   psum @ 0x61000 : 768 f32
//   pcnt @ 0x61C00 : 768 f32

// ---- K0: transpose E -> ET and compute sq[j]; 48 blocks x 16 rows ----
__global__ __launch_bounds__(256) void transpose_sq_kernel(
    const float* __restrict__ E, float* __restrict__ ET, float* __restrict__ sq)
{
    __shared__ float tile[16 * 129];
    __shared__ float part[16][17];
    const int b   = blockIdx.x;
    const int tid = threadIdx.x;

    const float4* src = (const float4*)(E + (size_t)b * 16 * ND);
    #pragma unroll
    for (int i = 0; i < 2; ++i) {
        int idx = tid + i * 256;            // 0..511 float4
        int r   = idx >> 5;                 // 32 float4 per row
        int c4  = idx & 31;
        float4 v = src[idx];                // coalesced
        tile[r * 129 + c4 * 4 + 0] = v.x;
        tile[r * 129 + c4 * 4 + 1] = v.y;
        tile[r * 129 + c4 * 4 + 2] = v.z;
        tile[r * 129 + c4 * 4 + 3] = v.w;
    }
    __syncthreads();

    // sq partials: thread (r,kk) sums 8 k's
    {
        int r = tid >> 4, kk = tid & 15;
        float s = 0.f;
        #pragma unroll
        for (int i = 0; i < 8; ++i) {
            float v = tile[r * 129 + kk * 8 + i];
            s += v * v;
        }
        part[r][kk] = s;
    }
    __syncthreads();
    if (tid < 16) {
        float s = 0.f;
        #pragma unroll
        for (int i = 0; i < 16; ++i) s += part[tid][i];
        sq[b * 16 + tid] = s;
    }

    // transposed writes: thread (jj, kh) writes 8 k's
    {
        int jj = tid & 15, kh = tid >> 4;   // kh 0..15
        #pragma unroll
        for (int ki = 0; ki < 8; ++ki) {
            int k = kh * 8 + ki;
            ET[(size_t)k * NB + b * 16 + jj] = tile[jj * 129 + k];  // 2-way LDS read (free)
        }
    }
}

// ---- K1: fused distance (coalesced ET reads) + mining; 256 blocks x 3 waves
__global__ __launch_bounds__(192) void triplet_fused_kernel(
    const float* __restrict__ E, const float* __restrict__ ET,
    const float* __restrict__ sq, const int* __restrict__ L,
    float* __restrict__ psum, float* __restrict__ pcnt)
{
    __shared__ float arow[APB][ND];        // 1.5 KB
    __shared__ float drow[APB][NB];        // 9 KB

    const int i0   = blockIdx.x * APB;
    const int tid  = threadIdx.x;
    const int lane = tid & 63;
    const int wave = tid >> 6;             // 0..2, wave = anchor

    // stage the 3 anchor rows (96 float4, coalesced)
    if (tid < APB * ND / 4)
        ((float4*)arow)[tid] = ((const float4*)(E + (size_t)i0 * ND))[tid];

    // labels -> masks (coalesced 256B int loads)
    const int ia = i0 + wave;
    const int li = L[ia];
    unsigned negm = 0u, posm = 0u;
    #pragma unroll
    for (int c = 0; c < NC; ++c) {
        int j = c * 64 + lane;
        int lj = L[j];
        if (lj != li)     negm |= (1u << c);
        else if (j != ia) posm |= (1u << c);
    }
    const float sqa = sq[ia];              // precomputed anchor norm
    __syncthreads();

    // ---- distance phase: float4-coalesced ET column reads ----
    // lane covers j = c*256 + lane*4 + q  (c = 0..2, q = 0..3)
    {
        const float4* Bf4 = (const float4*)ET + lane;   // + k*192 + c*64
        float4 acc0 = {0.f, 0.f, 0.f, 0.f};
        float4 acc1 = {0.f, 0.f, 0.f, 0.f};
        float4 acc2 = {0.f, 0.f, 0.f, 0.f};
        const float* ar = arow[wave];
        #pragma unroll 4
        for (int k = 0; k < ND; ++k) {
            float av  = ar[k];                          // uniform ds_read broadcast
            float4 b0 = Bf4[k * 192];
            float4 b1 = Bf4[k * 192 + 64];
            float4 b2 = Bf4[k * 192 + 128];
            acc0.x += av * b0.x; acc0.y += av * b0.y; acc0.z += av * b0.z; acc0.w += av * b0.w;
            acc1.x += av * b1.x; acc1.y += av * b1.y; acc1.z += av * b1.z; acc1.w += av * b1.w;
            acc2.x += av * b2.x; acc2.y += av * b2.y; acc2.z += av * b2.z; acc2.w += av * b2.w;
        }
        float4 sq0 = ((const float4*)sq)[lane];
        float4 sq1 = ((const float4*)sq)[lane + 64];
        float4 sq2 = ((const float4*)sq)[lane + 128];
        float4 d;
        d.x = sqrtf(fmaxf(sqa + sq0.x - 2.f * acc0.x, TL_EPS));
        d.y = sqrtf(fmaxf(sqa + sq0.y - 2.f * acc0.y, TL_EPS));
        d.z = sqrtf(fmaxf(sqa + sq0.z - 2.f * acc0.z, TL_EPS));
        d.w = sqrtf(fmaxf(sqa + sq0.w - 2.f * acc0.w, TL_EPS));
        *(float4*)&drow[wave][0 * 256 + lane * 4] = d;
        d.x = sqrtf(fmaxf(sqa + sq1.x - 2.f * acc1.x, TL_EPS));
        d.y = sqrtf(fmaxf(sqa + sq1.y - 2.f * acc1.y, TL_EPS));
        d.z = sqrtf(fmaxf(sqa + sq1.z - 2.f * acc1.z, TL_EPS));
        d.w = sqrtf(fmaxf(sqa + sq1.w - 2.f * acc1.w, TL_EPS));
        *(float4*)&drow[wave][1 * 256 + lane * 4] = d;
        d.x = sqrtf(fmaxf(sqa + sq2.x - 2.f * acc2.x, TL_EPS));
        d.y = sqrtf(fmaxf(sqa + sq2.y - 2.f * acc2.y, TL_EPS));
        d.z = sqrtf(fmaxf(sqa + sq2.z - 2.f * acc2.z, TL_EPS));
        d.w = sqrtf(fmaxf(sqa + sq2.w - 2.f * acc2.w, TL_EPS));
        *(float4*)&drow[wave][2 * 256 + lane * 4] = d;
    }
    // wave-local: same wave wrote drow[wave], no barrier needed

    // ---- mining (proven code, j = c*64 + lane register cache) ----
    float dk[NC];
    #pragma unroll
    for (int c = 0; c < NC; ++c) dk[c] = drow[wave][c * 64 + lane];

    float bv = INFINITY;
    #pragma unroll
    for (int c = 0; c < NC; ++c)
        if ((negm >> c) & 1u) bv = fminf(bv, dk[c]);
    #pragma unroll
    for (int off = 32; off > 0; off >>= 1)
        bv = fminf(bv, __shfl_xor(bv, off));
    const float hval = bv;

    float lsum = 0.f, lcnt = 0.f;
    if (isfinite(hval)) {
        #pragma unroll
        for (int c = 0; c < NC; ++c) {
            unsigned long long pm = __ballot((posm >> c) & 1u);
            while (pm) {
                const int sl = __builtin_ctzll(pm);
                pm &= pm - 1;
                const float pd = __shfl(dk[c], sl);
                float nd = hval;
                #pragma unroll
                for (int c2 = 0; c2 < NC; ++c2) {
                    bool pred = ((negm >> c2) & 1u) &&
                                (dk[c2] > pd) && (dk[c2] < pd + TL_MARGIN);
                    unsigned long long m = __ballot(pred);
                    if (m) { nd = __shfl(dk[c2], __builtin_ctzll(m)); break; }
                }
                lsum += fmaxf(pd - nd + TL_MARGIN, 0.f);
                lcnt += 1.f;
            }
        }
    }
    if (lane == 0) { psum[ia] = lsum; pcnt[ia] = lcnt; }
}

__global__ __launch_bounds__(64) void triplet_finalize_kernel(
    const float* __restrict__ psum, const float* __restrict__ pcnt,
    float* __restrict__ out)
{
    const int lane = threadIdx.x;
    float a = 0.f, b = 0.f;
    for (int j = lane; j < NB; j += 64) { a += psum[j]; b += pcnt[j]; }
    #pragma unroll
    for (int off = 32; off > 0; off >>= 1) {
        a += __shfl_xor(a, off);
        b += __shfl_xor(b, off);
    }
    if (lane == 0) out[0] = a / fmaxf(b, 1.f);
}

extern "C" void kernel_launch(void* const* d_in, const int* in_sizes, int n_in,
                              void* d_out, int out_size, void* d_ws, size_t ws_size,
                              hipStream_t stream) {
    const float* E = (const float*)d_in[0];
    const int*   L = (const int*)d_in[1];
    char* ws = (char*)d_ws;
    float* ET   = (float*)(ws);
    float* sq   = (float*)(ws + 0x60000);
    float* psum = (float*)(ws + 0x61000);
    float* pcnt = (float*)(ws + 0x61C00);
    float* out  = (float*)d_out;

    transpose_sq_kernel<<<NB / 16, 256, 0, stream>>>(E, ET, sq);
    triplet_fused_kernel<<<NB / APB, APB * 64, 0, stream>>>(E, ET, sq, L, psum, pcnt);
    triplet_finalize_kernel<<<1, 64, 0, stream>>>(psum, pcnt, out);
}

// Round 8
// 31.318 us; speedup vs baseline: 1.1854x; 1.1854x over previous
//
#include <hip/hip_runtime.h>
#include <math.h>

#define NB 768
#define ND 128
#define NC 12            // NB / 64 lane-chunks (mining layout)
#define APB 3            // anchors per block in K1 -> 256 blocks
#define TL_MARGIN 1.0f
#define TL_EPS 1e-12f

// ws layout (bytes):
//   ET @ 0x00000 : 128*768 f32 = 384 KB   (ET[k][j] = E[j][k])
//   sq @ 0x60000 : 768 f32
//   psum @ 0x61000 : 768 f32
//   pcnt @ 0x61C00 : 768 f32

// ---- K0: transpose + sq, high-TLP (384 blocks x 256 thr, 2 rows/block) ----
__global__ __launch_bounds__(256) void transpose_sq_kernel(
    const float* __restrict__ E, float* __restrict__ ET, float* __restrict__ sq)
{
    __shared__ float part[4];
    const int b    = blockIdx.x;
    const int tid  = threadIdx.x;
    const int lane = tid & 63;
    const int wave = tid >> 6;

    const int idx = b * 256 + tid;        // global element index, coalesced
    const float v = E[idx];
    const int j = idx >> 7;               // row
    const int k = idx & 127;              // col
    ET[(size_t)k * NB + j] = v;           // scattered store, fire-and-forget

    // wave w holds 64 consecutive k of row (2b + w/2); reduce v^2
    float s = v * v;
    #pragma unroll
    for (int off = 32; off > 0; off >>= 1) s += __shfl_xor(s, off);
    if (lane == 0) part[wave] = s;
    __syncthreads();
    if (tid == 0) {
        sq[2 * b]     = part[0] + part[1];
        sq[2 * b + 1] = part[2] + part[3];
    }
}

// ---- K1: fused distance + mining; 256 blocks x 384 thr (6 waves) ----
__global__ __launch_bounds__(384) void triplet_fused_kernel(
    const float* __restrict__ E, const float* __restrict__ ET,
    const float* __restrict__ sq, const int* __restrict__ L,
    float* __restrict__ psum, float* __restrict__ pcnt)
{
    __shared__ float drow[APB][NB];        // 9 KB

    const int tid  = threadIdx.x;
    const int lane = tid & 63;
    const int wave = tid >> 6;             // 0..5
    int i0 = blockIdx.x * APB;
    i0 = __builtin_amdgcn_readfirstlane(i0);

    // anchor rows via wave-uniform pointers -> scalar loads (no DS, no VMEM-v)
    const float* __restrict__ A0 = E + (size_t)(i0 + 0) * ND;
    const float* __restrict__ A1 = E + (size_t)(i0 + 1) * ND;
    const float* __restrict__ A2 = E + (size_t)(i0 + 2) * ND;
    const float sqa0 = sq[i0], sqa1 = sq[i0 + 1], sqa2 = sq[i0 + 2];

    // ---- distance: wave w covers j in [w*128, w*128+128), float2 per lane ----
    // ET as float2 rows of 384: elem (k, pair p) at k*384 + p ; p = wave*64+lane
    const float2* __restrict__ Bp = (const float2*)ET + (wave * 64 + lane);
    float px0 = 0.f, py0 = 0.f, px1 = 0.f, py1 = 0.f, px2 = 0.f, py2 = 0.f;
    #pragma unroll 8
    for (int k = 0; k < ND; ++k) {
        float2 b = Bp[(size_t)k * 384];    // coalesced 512 B per wave-instr
        float a0 = A0[k], a1 = A1[k], a2 = A2[k];   // SGPR broadcasts
        px0 += a0 * b.x; py0 += a0 * b.y;
        px1 += a1 * b.x; py1 += a1 * b.y;
        px2 += a2 * b.x; py2 += a2 * b.y;
    }
    const int j0 = wave * 128 + lane * 2;
    const float2 sj = *(const float2*)(sq + j0);
    {
        float2 d;
        d.x = sqrtf(fmaxf(sqa0 + sj.x - 2.f * px0, TL_EPS));
        d.y = sqrtf(fmaxf(sqa0 + sj.y - 2.f * py0, TL_EPS));
        *(float2*)&drow[0][j0] = d;
        d.x = sqrtf(fmaxf(sqa1 + sj.x - 2.f * px1, TL_EPS));
        d.y = sqrtf(fmaxf(sqa1 + sj.y - 2.f * py1, TL_EPS));
        *(float2*)&drow[1][j0] = d;
        d.x = sqrtf(fmaxf(sqa2 + sj.x - 2.f * px2, TL_EPS));
        d.y = sqrtf(fmaxf(sqa2 + sj.y - 2.f * py2, TL_EPS));
        *(float2*)&drow[2][j0] = d;
    }
    __syncthreads();

    // ---- mining: waves 0..2, wave = anchor (proven code) ----
    if (wave < APB) {
        const int ia = i0 + wave;
        const int li = L[ia];
        unsigned negm = 0u, posm = 0u;
        float dk[NC];
        #pragma unroll
        for (int c = 0; c < NC; ++c) {
            int j = c * 64 + lane;
            dk[c] = drow[wave][j];
            int lj = L[j];
            if (lj != li)     negm |= (1u << c);
            else if (j != ia) posm |= (1u << c);
        }

        float bv = INFINITY;
        #pragma unroll
        for (int c = 0; c < NC; ++c)
            if ((negm >> c) & 1u) bv = fminf(bv, dk[c]);
        #pragma unroll
        for (int off = 32; off > 0; off >>= 1)
            bv = fminf(bv, __shfl_xor(bv, off));
        const float hval = bv;

        float lsum = 0.f, lcnt = 0.f;
        if (isfinite(hval)) {
            #pragma unroll
            for (int c = 0; c < NC; ++c) {
                unsigned long long pm = __ballot((posm >> c) & 1u);
                while (pm) {
                    const int sl = __builtin_ctzll(pm);
                    pm &= pm - 1;
                    const float pd = __shfl(dk[c], sl);
                    float nd = hval;
                    #pragma unroll
                    for (int c2 = 0; c2 < NC; ++c2) {
                        bool pred = ((negm >> c2) & 1u) &&
                                    (dk[c2] > pd) && (dk[c2] < pd + TL_MARGIN);
                        unsigned long long m = __ballot(pred);
                        if (m) { nd = __shfl(dk[c2], __builtin_ctzll(m)); break; }
                    }
                    lsum += fmaxf(pd - nd + TL_MARGIN, 0.f);
                    lcnt += 1.f;
                }
            }
        }
        if (lane == 0) { psum[ia] = lsum; pcnt[ia] = lcnt; }
    }
}

__global__ __launch_bounds__(64) void triplet_finalize_kernel(
    const float* __restrict__ psum, const float* __restrict__ pcnt,
    float* __restrict__ out)
{
    const int lane = threadIdx.x;
    float a = 0.f, b = 0.f;
    for (int j = lane; j < NB; j += 64) { a += psum[j]; b += pcnt[j]; }
    #pragma unroll
    for (int off = 32; off > 0; off >>= 1) {
        a += __shfl_xor(a, off);
        b += __shfl_xor(b, off);
    }
    if (lane == 0) out[0] = a / fmaxf(b, 1.f);
}

extern "C" void kernel_launch(void* const* d_in, const int* in_sizes, int n_in,
                              void* d_out, int out_size, void* d_ws, size_t ws_size,
                              hipStream_t stream) {
    const float* E = (const float*)d_in[0];
    const int*   L = (const int*)d_in[1];
    char* ws = (char*)d_ws;
    float* ET   = (float*)(ws);
    float* sq   = (float*)(ws + 0x60000);
    float* psum = (float*)(ws + 0x61000);
    float* pcnt = (float*)(ws + 0x61C00);
    float* out  = (float*)d_out;

    transpose_sq_kernel<<<NB * ND / 256, 256, 0, stream>>>(E, ET, sq);
    triplet_fused_kernel<<<NB / APB, 384, 0, stream>>>(E, ET, sq, L, psum, pcnt);
    triplet_finalize_kernel<<<1, 64, 0, stream>>>(psum, pcnt, out);
}